// Round 11
// baseline (120.117 us; speedup 1.0000x reference)
//
#include <hip/hip_runtime.h>
#include <math.h>

#define D   128
#define LQ  256
#define KCQ 9
#define BQ  8
#define TQ  4096
#define RISK_DELTA 2e-5f
#define WCAP 16384

// ---------------- pk1: T2 = Wk^T@Wq, u = ctx_w^T@bias_w^T, transposed f32 tables ----
__global__ void pk1(const float* __restrict__ wk, const float* __restrict__ wq,
                    const float* __restrict__ ctx_w, const float* __restrict__ bias_w,
                    const float* __restrict__ conv_w, const float* __restrict__ val_b,
                    const float* __restrict__ lag_embed,
                    double* __restrict__ T2, double* __restrict__ u, int* __restrict__ wcnt,
                    float* __restrict__ ctx_wT, float* __restrict__ wqT,
                    float* __restrict__ conv_wT, float* __restrict__ baseT) {
    int tid = threadIdx.x;
    int bid = blockIdx.x;
    if (bid < D) {
        int d = bid;
        if (tid < D) {
            double acc = 0.0;
            for (int j = 0; j < D; ++j)
                acc += (double)wk[j * D + d] * (double)wq[j * D + tid];
            T2[d * D + tid] = acc;
            ctx_wT[d * D + tid] = ctx_w[tid * D + d];
            wqT[d * D + tid]    = wq[tid * D + d];
            if (d < KCQ) conv_wT[d * D + tid] = conv_w[tid * KCQ + d];
        }
        baseT[d * LQ + tid] = __fadd_rn(val_b[d], lag_embed[(size_t)(tid + 1) * D + d]);
    } else if (bid == D) {
        if (tid < D) {
            double acc = 0.0;
            for (int dd = 0; dd < D; ++dd)
                acc += (double)bias_w[dd] * (double)ctx_w[dd * D + tid];
            u[tid] = acc;
        }
    } else {
        if (tid == 0) *wcnt = 0;
    }
}

__global__ void pk2(const double* __restrict__ T2, const float* __restrict__ ctx_w,
                    const float* __restrict__ conv_w, const float* __restrict__ conv_b,
                    const float* __restrict__ ctx_b,
                    double* __restrict__ g, double* __restrict__ c1) {
    __shared__ double row[D];
    int d = blockIdx.x, e = threadIdx.x;
    double acc = 0.0;
    for (int j = 0; j < D; ++j)
        acc += T2[d * D + j] * (double)ctx_w[j * D + e];
    row[e] = acc;
    __syncthreads();
    if (e < KCQ) {
        double a = 0.0;
        for (int q = 0; q < D; ++q) a += row[q] * (double)conv_w[q * KCQ + e];
        g[e * D + d] = a;           // tap-major: g[k][d]
    } else if (e == KCQ) {
        double a = 0.0;
        for (int q = 0; q < D; ++q) a += row[q] * (double)conv_b[q];
        for (int q = 0; q < D; ++q) a += T2[d * D + q] * (double)ctx_b[q];
        c1[d] = a;
    }
}

__global__ void pk3(const float* __restrict__ lag_embed, const float* __restrict__ val_b,
                    const float* __restrict__ val_w, const float* __restrict__ conv_w,
                    const float* __restrict__ conv_b, const float* __restrict__ ctx_b,
                    const float* __restrict__ bias_w, const float* __restrict__ bias_b,
                    const double* __restrict__ g, const double* __restrict__ c1,
                    const double* __restrict__ u,
                    double* __restrict__ gbT, double* __restrict__ cbv, double* __restrict__ cst) {
    int tid = threadIdx.x;
    if (blockIdx.x < LQ) {
        __shared__ double bl[D];
        int l = blockIdx.x;
        bl[tid] = (double)val_b[tid] + (double)lag_embed[(l + 1) * D + tid];
        __syncthreads();
        if (tid < KCQ) {
            double a = 0.0;
            for (int q = 0; q < D; ++q) a += bl[q] * g[tid * D + q];
            gbT[tid * LQ + l] = a;
        } else if (tid == KCQ) {
            double a = 0.0;
            for (int q = 0; q < D; ++q) a += bl[q] * c1[q];
            cbv[l] = a;
        }
    } else {
        if (tid < KCQ) {
            double a = 0.0, a2 = 0.0;
            for (int q = 0; q < D; ++q) a  += g[tid * D + q] * (double)val_w[q];
            for (int q = 0; q < D; ++q) a2 += u[q] * (double)conv_w[q * KCQ + tid];
            cst[tid]      = a;    // sk[k]
            cst[10 + tid] = a2;   // hk[k]
        } else if (tid == KCQ) {
            double a = 0.0, a2 = 0.0;
            for (int q = 0; q < D; ++q) a  += c1[q] * (double)val_w[q];
            for (int q = 0; q < D; ++q) a2 += u[q] * (double)conv_b[q];
            for (int q = 0; q < D; ++q) a2 += (double)bias_w[q] * (double)ctx_b[q];
            cst[9]  = a;                          // ssc
            cst[19] = a2 + (double)bias_b[0];     // hc (incl. bias_b)
        }
    }
}

// ---------------- main kernel (round-5 form; only change: min 8 waves/EU) ----------
__global__ __launch_bounds__(256, 8) void lag_main(
    const float* __restrict__ x, const double* __restrict__ gbT,
    const double* __restrict__ cbv, const double* __restrict__ cst,
    float* __restrict__ muOut, float* __restrict__ wOut,
    int* __restrict__ wcnt, int* __restrict__ wlist) {
    __shared__ float sgb[KCQ * LQ];
    __shared__ float scb[LQ];
    __shared__ float sc[20];
    int tid = threadIdx.x;
    #pragma unroll
    for (int i = 0; i < KCQ; ++i) sgb[i * LQ + tid] = (float)gbT[i * LQ + tid];
    scb[tid] = (float)cbv[tid];
    if (tid < 20) sc[tid] = (float)cst[tid];
    __syncthreads();

    int wave = tid >> 6, lane = tid & 63;
    int row = blockIdx.x * 4 + wave;
    int b = row >> 12;
    int t = row & (TQ - 1);
    const float* xb = x + b * TQ;

    float xw[KCQ];
    #pragma unroll
    for (int k = 0; k < KCQ; ++k) {
        int idx = t - 8 + k;
        xw[k] = (idx >= 0) ? xb[idx] : 0.f;
    }
    float s = sc[9], bias = sc[19];
    #pragma unroll
    for (int k = 0; k < KCQ; ++k) {
        s    = fmaf(sc[k],      xw[k], s);
        bias = fmaf(sc[10 + k], xw[k], bias);
    }

    int l0 = lane * 4;
    float xlag[4];
    #pragma unroll
    for (int i = 0; i < 4; ++i) {
        int idx = t - 1 - (l0 + i);
        xlag[i] = (idx >= 0) ? xb[idx] : 0.f;
    }

    float4 cb4 = *reinterpret_cast<const float4*>(&scb[l0]);
    float lg[4] = {cb4.x, cb4.y, cb4.z, cb4.w};
    #pragma unroll
    for (int k = 0; k < KCQ; ++k) {
        float4 g4 = *reinterpret_cast<const float4*>(&sgb[k * LQ + l0]);
        lg[0] = fmaf(g4.x, xw[k], lg[0]);
        lg[1] = fmaf(g4.y, xw[k], lg[1]);
        lg[2] = fmaf(g4.z, xw[k], lg[2]);
        lg[3] = fmaf(g4.w, xw[k], lg[3]);
    }
    #pragma unroll
    for (int i = 0; i < 4; ++i) lg[i] = fmaf(xlag[i], s, lg[i]);

    // top-9 extraction (f32): v1 (mx), v8 (thr), v9 (risk gap)
    const float NEG_INF = -__builtin_inff();
    float wl0 = lg[0], wl1 = lg[1], wl2 = lg[2], wl3 = lg[3];
    float mx = 0.f, thr = 0.f, v9 = 0.f;
    #pragma unroll
    for (int it = 0; it < 9; ++it) {
        float lm = fmaxf(fmaxf(wl0, wl1), fmaxf(wl2, wl3));
        float m = lm;
        #pragma unroll
        for (int off = 32; off >= 1; off >>= 1)
            m = fmaxf(m, __shfl_xor(m, off, 64));
        if (it == 0) mx = m;
        if (it == 7) thr = m;
        if (it == 8) v9 = m;
        if (it < 8) {
            unsigned long long ball = __ballot(lm == m);
            int leader = __ffsll(ball) - 1;
            if (lane == leader) {
                if (wl0 == m)      wl0 = NEG_INF;
                else if (wl1 == m) wl1 = NEG_INF;
                else if (wl2 == m) wl2 = NEG_INF;
                else               wl3 = NEG_INF;
            }
        }
    }

    if ((thr - v9) < RISK_DELTA) {
        if (lane == 0) {
            int pos = atomicAdd(wcnt, 1);
            if (pos < WCAP) wlist[pos] = row;
        }
        return;
    }

    float p[4], psum = 0.f, pmu = 0.f;
    #pragma unroll
    for (int j = 0; j < 4; ++j) {
        p[j] = (lg[j] >= thr) ? __expf(lg[j] - mx) : 0.f;
        psum += p[j];
        pmu = fmaf(p[j], xlag[j], pmu);
    }
    #pragma unroll
    for (int off = 32; off >= 1; off >>= 1) {
        psum += __shfl_xor(psum, off, 64);
        pmu  += __shfl_xor(pmu,  off, 64);
    }
    float inv = 1.f / psum;
    float4 wo = make_float4(p[0] * inv, p[1] * inv, p[2] * inv, p[3] * inv);
    *reinterpret_cast<float4*>(&wOut[(size_t)row * LQ + l0]) = wo;
    if (lane == 0) muOut[row] = fmaf(pmu, inv, bias);
}

// ---------------- fixer: np-faithful fp32 pipeline, 16 rows/block ------------------
// Per-accumulator arithmetic bit-identical to the proven arbiter-matcher (sequential
// f32 FMA, ascending index; __fadd_rn/__fmul_rn at materialization points). 8 rows
// per thread-halfgroup -> 128 FMAs per load-batch hide most of the batch latency.
__global__ __launch_bounds__(256) void fixer(
    const float* __restrict__ x, const float* __restrict__ wk,
    const float* __restrict__ val_w, const float* __restrict__ conv_b,
    const float* __restrict__ ctx_b, const float* __restrict__ bias_w,
    const float* __restrict__ bias_b,
    const float* __restrict__ ctx_wT, const float* __restrict__ wqT,
    const float* __restrict__ conv_wT, const float* __restrict__ baseT,
    const int* __restrict__ wcnt, const int* __restrict__ wlist,
    float* __restrict__ muOut, float* __restrict__ wOut) {
    __shared__ float sxw[16][KCQ];
    __shared__ float sctxc[16][D];
    __shared__ float sctxp[16][D];
    __shared__ float sq[16][D];
    __shared__ float sqk[16][D];
    __shared__ float ssv[16];
    __shared__ float sbd[16];
    __shared__ float slog[16][LQ];
    __shared__ int   srow[16];

    int cnt = *wcnt;
    if (cnt > WCAP) cnt = WCAP;
    int ngroups = (cnt + 15) >> 4;
    int tid = threadIdx.x;

    for (int gi = blockIdx.x; gi < ngroups; gi += gridDim.x) {
        if (tid < 16) {
            int idx = gi * 16 + tid;
            if (idx >= cnt) idx = cnt - 1;   // pad with last row (duplicate write is benign)
            srow[tid] = wlist[idx];
        }
        __syncthreads();
        if (tid < 16 * KCQ) {
            int g = tid / KCQ, k = tid % KCQ;
            int row = srow[g]; int b = row >> 12, t = row & (TQ - 1);
            int ii = t - 8 + k;
            sxw[g][k] = (ii >= 0) ? x[b * TQ + ii] : 0.f;
        }
        __syncthreads();

        // stage 1: causal conv — sequential f32 FMA over k (9 taps)
        {
            int d = tid & (D - 1), gh = tid >> 7;
            float cw[KCQ];
            #pragma unroll
            for (int k = 0; k < KCQ; ++k) cw[k] = conv_wT[k * D + d];
            #pragma unroll 1
            for (int g = gh * 8; g < gh * 8 + 8; ++g) {
                float a = 0.f;
                #pragma unroll
                for (int k = 0; k < KCQ; ++k)
                    a = fmaf(cw[k], sxw[g][k], a);
                sctxc[g][d] = __fadd_rn(a, conv_b[d]);
            }
        }
        __syncthreads();

        // stage 2: ctx_proj — 8 accs/thread, dbuf 16-batches
        {
            int e = tid & (D - 1), gh = tid >> 7, g0 = gh * 8;
            float acc[8];
            #pragma unroll
            for (int r = 0; r < 8; ++r) acc[r] = 0.f;
            float wv0[16], wv1[16];
            #pragma unroll
            for (int u = 0; u < 16; ++u) wv0[u] = ctx_wT[u * D + e];
            #pragma unroll 1
            for (int d2 = 0; d2 < D; d2 += 32) {
                #pragma unroll
                for (int u = 0; u < 16; ++u) wv1[u] = ctx_wT[(d2 + 16 + u) * D + e];
                #pragma unroll
                for (int u = 0; u < 16; ++u) {
                    float w = wv0[u];
                    #pragma unroll
                    for (int r = 0; r < 8; ++r) acc[r] = fmaf(w, sctxc[g0 + r][d2 + u], acc[r]);
                }
                if (d2 + 32 < D) {
                    #pragma unroll
                    for (int u = 0; u < 16; ++u) wv0[u] = ctx_wT[(d2 + 32 + u) * D + e];
                }
                #pragma unroll
                for (int u = 0; u < 16; ++u) {
                    float w = wv1[u];
                    #pragma unroll
                    for (int r = 0; r < 8; ++r) acc[r] = fmaf(w, sctxc[g0 + r][d2 + 16 + u], acc[r]);
                }
            }
            float cb = ctx_b[e];
            #pragma unroll
            for (int r = 0; r < 8; ++r) sctxp[g0 + r][e] = __fadd_rn(acc[r], cb);
        }
        __syncthreads();

        // stage 3: q = ctx @ wq.T — same pattern with wqT
        {
            int e = tid & (D - 1), gh = tid >> 7, g0 = gh * 8;
            float acc[8];
            #pragma unroll
            for (int r = 0; r < 8; ++r) acc[r] = 0.f;
            float wv0[16], wv1[16];
            #pragma unroll
            for (int u = 0; u < 16; ++u) wv0[u] = wqT[u * D + e];
            #pragma unroll 1
            for (int e2 = 0; e2 < D; e2 += 32) {
                #pragma unroll
                for (int u = 0; u < 16; ++u) wv1[u] = wqT[(e2 + 16 + u) * D + e];
                #pragma unroll
                for (int u = 0; u < 16; ++u) {
                    float w = wv0[u];
                    #pragma unroll
                    for (int r = 0; r < 8; ++r) acc[r] = fmaf(w, sctxp[g0 + r][e2 + u], acc[r]);
                }
                if (e2 + 32 < D) {
                    #pragma unroll
                    for (int u = 0; u < 16; ++u) wv0[u] = wqT[(e2 + 32 + u) * D + e];
                }
                #pragma unroll
                for (int u = 0; u < 16; ++u) {
                    float w = wv1[u];
                    #pragma unroll
                    for (int r = 0; r < 8; ++r) acc[r] = fmaf(w, sctxp[g0 + r][e2 + 16 + u], acc[r]);
                }
            }
            #pragma unroll
            for (int r = 0; r < 8; ++r) sq[g0 + r][e] = acc[r];
        }
        __syncthreads();

        // stage 4: qk = q @ wk — same pattern (wk column-coalesced already)
        {
            int e = tid & (D - 1), gh = tid >> 7, g0 = gh * 8;
            float acc[8];
            #pragma unroll
            for (int r = 0; r < 8; ++r) acc[r] = 0.f;
            float wv0[16], wv1[16];
            #pragma unroll
            for (int u = 0; u < 16; ++u) wv0[u] = wk[u * D + e];
            #pragma unroll 1
            for (int a2i = 0; a2i < D; a2i += 32) {
                #pragma unroll
                for (int u = 0; u < 16; ++u) wv1[u] = wk[(a2i + 16 + u) * D + e];
                #pragma unroll
                for (int u = 0; u < 16; ++u) {
                    float w = wv0[u];
                    #pragma unroll
                    for (int r = 0; r < 8; ++r) acc[r] = fmaf(w, sq[g0 + r][a2i + u], acc[r]);
                }
                if (a2i + 32 < D) {
                    #pragma unroll
                    for (int u = 0; u < 16; ++u) wv0[u] = wk[(a2i + 32 + u) * D + e];
                }
                #pragma unroll
                for (int u = 0; u < 16; ++u) {
                    float w = wv1[u];
                    #pragma unroll
                    for (int r = 0; r < 8; ++r) acc[r] = fmaf(w, sq[g0 + r][a2i + 16 + u], acc[r]);
                }
            }
            #pragma unroll
            for (int r = 0; r < 8; ++r) sqk[g0 + r][e] = acc[r];
        }
        __syncthreads();

        // s = qk·val_w (tid<16) ; biasdot = ctxp·bias_w (tid 16..31)
        if (tid < 16) {
            int g = tid;
            float a = 0.f;
            #pragma unroll 1
            for (int d2 = 0; d2 < D; d2 += 16) {
                float vv[16];
                #pragma unroll
                for (int u = 0; u < 16; ++u) vv[u] = val_w[d2 + u];
                #pragma unroll
                for (int u = 0; u < 16; ++u) a = fmaf(sqk[g][d2 + u], vv[u], a);
            }
            ssv[g] = a;
        } else if (tid < 32) {
            int g = tid - 16;
            float a = 0.f;
            #pragma unroll 1
            for (int e2 = 0; e2 < D; e2 += 16) {
                float vv[16];
                #pragma unroll
                for (int u = 0; u < 16; ++u) vv[u] = bias_w[e2 + u];
                #pragma unroll
                for (int u = 0; u < 16; ++u) a = fmaf(sctxp[g][e2 + u], vv[u], a);
            }
            sbd[g] = a;
        }
        __syncthreads();

        // logits: blog[l=tid] for 16 rows, dbuf loads; then combine with xlag
        {
            int l = tid;
            float c[16];
            #pragma unroll
            for (int r = 0; r < 16; ++r) c[r] = 0.f;
            float bd0[16], bd1[16];
            #pragma unroll
            for (int u = 0; u < 16; ++u) bd0[u] = baseT[u * LQ + l];
            #pragma unroll 1
            for (int d2 = 0; d2 < D; d2 += 32) {
                #pragma unroll
                for (int u = 0; u < 16; ++u) bd1[u] = baseT[(d2 + 16 + u) * LQ + l];
                #pragma unroll
                for (int u = 0; u < 16; ++u) {
                    float bd = bd0[u];
                    #pragma unroll
                    for (int r = 0; r < 16; ++r) c[r] = fmaf(bd, sqk[r][d2 + u], c[r]);
                }
                if (d2 + 32 < D) {
                    #pragma unroll
                    for (int u = 0; u < 16; ++u) bd0[u] = baseT[(d2 + 32 + u) * LQ + l];
                }
                #pragma unroll
                for (int u = 0; u < 16; ++u) {
                    float bd = bd1[u];
                    #pragma unroll
                    for (int r = 0; r < 16; ++r) c[r] = fmaf(bd, sqk[r][d2 + 16 + u], c[r]);
                }
            }
            #pragma unroll
            for (int g = 0; g < 16; ++g) {
                int row = srow[g]; int b = row >> 12, t = row & (TQ - 1);
                int ii = t - 1 - l;
                float xl = (ii >= 0) ? x[b * TQ + ii] : 0.f;
                slog[g][l] = __fadd_rn(__fmul_rn(xl, ssv[g]), c[g]);
            }
        }
        __syncthreads();

        // per-row f32 top-8 + f32 softmax + writes; wave handles 4 rows
        {
            int wv = tid >> 6, lane = tid & 63;
            #pragma unroll 1
            for (int gg = wv * 4; gg < wv * 4 + 4; ++gg) {
                float lv0 = slog[gg][lane], lv1 = slog[gg][lane + 64];
                float lv2 = slog[gg][lane + 128], lv3 = slog[gg][lane + 192];
                const float NEG_INF = -__builtin_inff();
                float w0 = lv0, w1 = lv1, w2 = lv2, w3 = lv3;
                float mx = 0.f, thr = 0.f;
                #pragma unroll
                for (int it = 0; it < 8; ++it) {
                    float lm = fmaxf(fmaxf(w0, w1), fmaxf(w2, w3));
                    float m = lm;
                    #pragma unroll
                    for (int off = 32; off >= 1; off >>= 1)
                        m = fmaxf(m, __shfl_xor(m, off, 64));
                    if (it == 0) mx = m;
                    thr = m;
                    if (it < 7) {
                        unsigned long long ball = __ballot(lm == m);
                        int leader = __ffsll(ball) - 1;
                        if (lane == leader) {
                            if (w0 == m)      w0 = NEG_INF;
                            else if (w1 == m) w1 = NEG_INF;
                            else if (w2 == m) w2 = NEG_INF;
                            else              w3 = NEG_INF;
                        }
                    }
                }
                int row = srow[gg]; int b = row >> 12, t = row & (TQ - 1);
                float p[4], xlg[4];
                double ps = 0.0;
                float lvs[4] = {lv0, lv1, lv2, lv3};
                #pragma unroll
                for (int j = 0; j < 4; ++j) {
                    int l = lane + 64 * j;
                    int ii = t - 1 - l;
                    xlg[j] = (ii >= 0) ? x[b * TQ + ii] : 0.f;
                    p[j] = (lvs[j] >= thr) ? (float)exp((double)__fsub_rn(lvs[j], mx)) : 0.f;
                    ps += (double)p[j];
                }
                #pragma unroll
                for (int off = 32; off >= 1; off >>= 1)
                    ps += __shfl_xor(ps, off, 64);
                float psf = (float)ps;
                double mud = 0.0;
                #pragma unroll
                for (int j = 0; j < 4; ++j) {
                    float wvv = __fdiv_rn(p[j], psf);
                    wOut[(size_t)row * LQ + lane + 64 * j] = wvv;
                    mud += (double)__fmul_rn(wvv, xlg[j]);
                }
                #pragma unroll
                for (int off = 32; off >= 1; off >>= 1)
                    mud += __shfl_xor(mud, off, 64);
                if (lane == 0) {
                    float m1 = (float)mud;
                    m1 = __fadd_rn(m1, sbd[gg]);
                    m1 = __fadd_rn(m1, bias_b[0]);
                    muOut[row] = m1;
                }
            }
        }
        __syncthreads();
    }
}

extern "C" void kernel_launch(void* const* d_in, const int* in_sizes, int n_in,
                              void* d_out, int out_size, void* d_ws, size_t ws_size,
                              hipStream_t stream) {
    const float* x         = (const float*)d_in[0];
    const float* lag_embed = (const float*)d_in[1];
    const float* val_w     = (const float*)d_in[2];
    const float* val_b     = (const float*)d_in[3];
    const float* conv_w    = (const float*)d_in[4];
    const float* conv_b    = (const float*)d_in[5];
    const float* ctx_w     = (const float*)d_in[6];
    const float* ctx_b     = (const float*)d_in[7];
    const float* wq        = (const float*)d_in[8];
    const float* wk        = (const float*)d_in[9];
    const float* bias_w    = (const float*)d_in[10];
    const float* bias_b    = (const float*)d_in[11];

    char* wsb = (char*)d_ws;
    double* T2  = (double*)wsb;     // 16384 d
    double* g   = T2 + 16384;       // 1152
    double* u   = g + 1152;         // 128
    double* c1  = u + 128;          // 128
    double* gbT = c1 + 128;         // 2304
    double* cbv = gbT + 2304;       // 256
    double* cst = cbv + 256;        // 20
    int* wcnt  = (int*)(wsb + 163840);
    int* wlist = wcnt + 1;          // WCAP=16384 ints
    float* ctx_wT  = (float*)(wsb + 229504);   // 16384 f
    float* wqT     = ctx_wT + 16384;           // 16384 f
    float* conv_wT = wqT + 16384;              // 1152 f
    float* baseT   = conv_wT + 1152;           // 32768 f

    float* muOut = (float*)d_out;
    float* wOut  = muOut + BQ * TQ;

    hipLaunchKernelGGL(pk1, dim3(D + 2), dim3(256), 0, stream,
                       wk, wq, ctx_w, bias_w, conv_w, val_b, lag_embed,
                       T2, u, wcnt, ctx_wT, wqT, conv_wT, baseT);
    hipLaunchKernelGGL(pk2, dim3(D), dim3(D), 0, stream, T2, ctx_w, conv_w, conv_b, ctx_b, g, c1);
    hipLaunchKernelGGL(pk3, dim3(LQ + 1), dim3(D), 0, stream,
                       lag_embed, val_b, val_w, conv_w, conv_b, ctx_b, bias_w, bias_b,
                       g, c1, u, gbT, cbv, cst);
    hipLaunchKernelGGL(lag_main, dim3(BQ * TQ / 4), dim3(256), 0, stream,
                       x, gbT, cbv, cst, muOut, wOut, wcnt, wlist);
    hipLaunchKernelGGL(fixer, dim3(64), dim3(256), 0, stream,
                       x, wk, val_w, conv_b, ctx_b, bias_w, bias_b,
                       ctx_wT, wqT, conv_wT, baseT, wcnt, wlist, muOut, wOut);
}